// Round 14
// baseline (673.833 us; speedup 1.0000x reference)
//
#include <hip/hip_runtime.h>
#include <hip/hip_bf16.h>
#include <cstdint>

#define NN    50000
#define NE    1600000
#define NG    512
#define F     64        // ATOM_FEA
#define ED    32        // EDGE_DIM
#define ZIN   160       // 2F + ED
#define NC    128       // fused Wf|Ws output cols
#define HF    128       // H_FEA
#define NCONV 3
#define BN_EPS 1e-5f
#define NWG   (NE / 256)   // 6250 k_edges workgroups
#define NPX   (NN / 8)     // 6250 nodes per XCD partition
#define SCB   98           // scan blocks: 98*512 = 50176 >= NN

typedef __bf16 bf16_t;
typedef bf16_t bf16x8 __attribute__((ext_vector_type(8)));
typedef float  f32x16 __attribute__((ext_vector_type(16)));

__global__ void k_embed_hist(const int* __restrict__ x, const float* __restrict__ emb,
                             float4* __restrict__ h4, ushort4* __restrict__ hb4,
                             const int* __restrict__ ei, int* __restrict__ cnt,
                             float4* __restrict__ agg4) {
  int i = blockIdx.x * 256 + threadIdx.x;          // 800000 lanes
  if (i < NN * F / 4) {
    int node = i >> 4, c4 = (i * 4) & 63;
    float4 v = *(const float4*)(emb + x[node] * F + c4);
    h4[i] = v;
    union { bf16_t h[4]; ushort4 u; } pk;
    pk.h[0] = (bf16_t)v.x; pk.h[1] = (bf16_t)v.y; pk.h[2] = (bf16_t)v.z; pk.h[3] = (bf16_t)v.w;
    hb4[i] = pk.u;
    agg4[i] = make_float4(0.f, 0.f, 0.f, 0.f);     // replaces separate memset (covers poison)
  }
  if (i < NE / 2) {
    atomicAdd(&cnt[ei[NE + i]], 1);
    atomicAdd(&cnt[ei[NE + i + NE / 2]], 1);
  }
}

// Wt layout: pre-fragmented for 32x32x16 MFMA B-operand, per layer:
//   Wt[((l*10 + ks)*4 + n)*512 + lane*8 + idx]
//   lane: g=lane>>5, lr=lane&31; col c = n*32+lr; k = 16*ks + 4*g + 8*(idx>>2) + (idx&3)
__global__ void k_wprep(const float* __restrict__ Wf, const float* __restrict__ Ws,
                        bf16_t* __restrict__ Wt) {
  int i = blockIdx.x * 256 + threadIdx.x;  // NCONV*ZIN*NC = 61440
  if (i >= NCONV * ZIN * NC) return;
  int l = i / 20480, r = i % 20480;
  int ks = r / 2048, r2 = r % 2048;
  int n = r2 / 512, r3 = r2 % 512;
  int lane = r3 >> 3, idx = r3 & 7;
  int g = lane >> 5, lr = lane & 31;
  int c = n * 32 + lr;
  int k = 16 * ks + 4 * g + 8 * (idx >> 2) + (idx & 3);
  float v = (c < F) ? Wf[(l * ZIN + k) * F + c] : Ws[(l * ZIN + k) * F + (c - F)];
  Wt[i] = (bf16_t)v;
}

// scan phase A: per-block exclusive scan (512 nodes/block) + block total
__global__ void k_scanA(const int* __restrict__ cnt, int* __restrict__ head,
                        int* __restrict__ bsum) {
  __shared__ int ts[512];
  const int b = blockIdx.x, t = threadIdx.x, i = b * 512 + t;
  int v = (i < NN) ? cnt[i] : 0;
  ts[t] = v;
  __syncthreads();
  for (int d = 1; d < 512; d <<= 1) {
    int xv = (t >= d) ? ts[t - d] : 0;
    __syncthreads();
    ts[t] += xv;
    __syncthreads();
  }
  if (i < NN) head[i] = ts[t] - v;       // block-local exclusive prefix
  if (t == 511) bsum[b] = ts[t];         // block total
}

// scan phase B: exclusive scan of the 98 block totals (in place)
__global__ void k_scanB(int* __restrict__ bsum) {
  __shared__ int ts[128];
  const int t = threadIdx.x;
  int v = (t < SCB) ? bsum[t] : 0;
  ts[t] = v;
  __syncthreads();
  for (int d = 1; d < 128; d <<= 1) {
    int xv = (t >= d) ? ts[t - d] : 0;
    __syncthreads();
    ts[t] += xv;
    __syncthreads();
  }
  if (t < SCB) bsum[t] = ts[t] - v;
}

// XCD-partitioned permutation + ea convert, fused (R13 proved within-XCD scattered
// writes don't amplify; eas row = 64B = one full line per thread). Block b covers
// edge-chunk b>>3, accepts only edges whose dst is owned by XCD b&7.
__global__ void k_scatter_ea(const int* __restrict__ ei, int* __restrict__ head,
                             const int* __restrict__ bsum, const float* __restrict__ ea,
                             int* __restrict__ dsts, int* __restrict__ srcs,
                             bf16_t* __restrict__ eas) {
  const int xcd = blockIdx.x & 7;
  const int e   = (blockIdx.x >> 3) * 256 + threadIdx.x;
  const int d   = ei[NE + e];
  if (d / NPX != xcd) return;
  const int p = atomicAdd(&head[d], 1) + bsum[d >> 9];
  dsts[p] = d;
  srcs[p] = ei[e];
  const float* pa = ea + (size_t)e * ED;
  bf16_t* pe = eas + (size_t)p * ED;
  #pragma unroll
  for (int q = 0; q < ED; q += 8) {
    float4 x0 = *(const float4*)(pa + q), x1 = *(const float4*)(pa + q + 4);
    union { bf16_t h[8]; uint4 u; } pk;
    pk.h[0] = (bf16_t)x0.x; pk.h[1] = (bf16_t)x0.y; pk.h[2] = (bf16_t)x0.z; pk.h[3] = (bf16_t)x0.w;
    pk.h[4] = (bf16_t)x1.x; pk.h[5] = (bf16_t)x1.y; pk.h[6] = (bf16_t)x1.z; pk.h[7] = (bf16_t)x1.w;
    *(uint4*)(pe + q) = pk.u;
  }
}

// 512 threads, 8 waves, 256 edges/block (32 edge-rows per wave) — R10/R13's proven structure.
// Registers: ~60 arch VGPR + 64 AGPR acc = ~124/thread -> 2 blocks/CU is the structural ceiling
// (R4 & R11 both proved forcing 6 waves/EU spills to scratch: WRITE_SIZE 0.5-3.4 GB).
// LDS: Bsh 40960 only. One barrier. Epilogue + segmented reduction fully in registers.
__launch_bounds__(512, 4)
__global__ void k_edges(const int* __restrict__ srcs, const int* __restrict__ dsts,
                        const bf16_t* __restrict__ eas, const bf16_t* __restrict__ hb,
                        const bf16_t* __restrict__ Wt,
                        const float* __restrict__ bfv, const float* __restrict__ bsv,
                        float* __restrict__ agg, int layer) {
  extern __shared__ char smem[];
  bf16_t* Bsh = (bf16_t*)smem;                       // [20480] pre-fragmented W

  const int tid = threadIdx.x;

  // bijective XCD-chunked swizzle: consecutive work -> same XCD (sorted-dst L2 locality)
  // NWG = 6250 = 8*781 + 2 -> q=781, r=2
  const int orig = blockIdx.x;
  const int xcd  = orig & 7;
  const int wg   = ((xcd < 2) ? xcd * 782 : 2 * 782 + (xcd - 2) * 781) + (orig >> 3);
  const int e0   = wg * 256;

  const int w  = tid >> 6;
  const int l  = tid & 63;
  const int lr = l & 31;
  const int g  = l >> 5;
  const int e  = w * 32 + lr;

  // long-latency loads first
  const int dv = dsts[e0 + e];
  const int sv = srcs[e0 + e];

  // per-lane bias values (folded into acc init via MFMA C-in)
  const float* bfl = bfv + layer * F;
  const float* bsl = bsv + layer * F;
  const float b0 = bfl[lr], b1 = bfl[lr + 32];
  const float s0b = bsl[lr], s1b = bsl[lr + 32];

  // gather A-fragments straight from global (fragment layout: lane=row, 8B strided by g-half)
  const char* dp = (const char*)(hb + (size_t)dv * F);
  const char* sp = (const char*)(hb + (size_t)sv * F);
  const char* ep = (const char*)(eas + (size_t)(e0 + e) * ED);
  uint2 dq[8], sq[8], eq[4];
  #pragma unroll
  for (int j = 0; j < 8; ++j) dq[j] = *(const uint2*)(dp + (2 * j + g) * 8);
  #pragma unroll
  for (int j = 0; j < 8; ++j) sq[j] = *(const uint2*)(sp + (2 * j + g) * 8);
  #pragma unroll
  for (int j = 0; j < 4; ++j) eq[j] = *(const uint2*)(ep + (2 * j + g) * 8);

  // stage B: 40960 B = 2560 uint4, 5 per thread
  {
    const uint4* Wg = (const uint4*)(Wt + (size_t)layer * NC * ZIN);
    uint4 breg[5];
    #pragma unroll
    for (int t = 0; t < 5; ++t) breg[t] = Wg[tid + t * 512];
    uint4* Bv = (uint4*)Bsh;
    #pragma unroll
    for (int t = 0; t < 5; ++t) Bv[tid + t * 512] = breg[t];
  }
  __syncthreads();   // the ONLY barrier: Bsh visible to all waves

  f32x16 acc[4];
  #pragma unroll
  for (int q = 0; q < 16; ++q) { acc[0][q] = b0; acc[1][q] = b1; acc[2][q] = s0b; acc[3][q] = s1b; }

  // independent-wave regime post-barrier -> setprio around MFMA cluster
  __builtin_amdgcn_s_setprio(1);
  #pragma unroll
  for (int ks = 0; ks < 10; ++ks) {
    union { uint2 u[2]; bf16x8 v; } a;
    a.u[0] = (ks < 4) ? dq[2 * ks]     : (ks < 8) ? sq[2 * (ks - 4)]     : eq[2 * (ks - 8)];
    a.u[1] = (ks < 4) ? dq[2 * ks + 1] : (ks < 8) ? sq[2 * (ks - 4) + 1] : eq[2 * (ks - 8) + 1];
    #pragma unroll
    for (int n = 0; n < 4; ++n) {
      bf16x8 b = *(const bf16x8*)(Bsh + ((ks * 4 + n) * 64 + l) * 8);  // ds_read_b128, stride-1
      acc[n] = __builtin_amdgcn_mfma_f32_32x32x16_bf16(a.v, b, acc[n], 0, 0, 0);
    }
  }
  __builtin_amdgcn_s_setprio(0);

  // epilogue in registers: mv0[q] = m[row(q,g)][lr], mv1[q] = m[row(q,g)][32+lr]
  const float L2E = 1.4426950408889634f, LN2 = 0.6931471805599453f;
  float mv0[16], mv1[16];
  #pragma unroll
  for (int q = 0; q < 16; ++q) {
    float f0 = acc[0][q], f1 = acc[1][q];
    float s2a = acc[2][q], s2c = acc[3][q];
    float sg0 = __builtin_amdgcn_rcpf(1.0f + __builtin_amdgcn_exp2f(-f0 * L2E));
    float sg1 = __builtin_amdgcn_rcpf(1.0f + __builtin_amdgcn_exp2f(-f1 * L2E));
    float sp0 = fmaxf(s2a, 0.0f) + __builtin_amdgcn_logf(1.0f + __builtin_amdgcn_exp2f(-fabsf(s2a) * L2E)) * LN2;
    float sp1 = fmaxf(s2c, 0.0f) + __builtin_amdgcn_logf(1.0f + __builtin_amdgcn_exp2f(-fabsf(s2c) * L2E)) * LN2;
    mv0[q] = sg0 * sp0;
    mv1[q] = sg1 * sp1;
  }

  // in-register segmented reduction over sorted-dst runs within this wave's 32-row window
  {
    const int dvp = __shfl(dv, l - 1);   // previous row's dst (lr>0 only)
    uint32_t bmask = ((uint32_t)__ballot(lr > 0 && dv != dvp)) | 1u;
    while (bmask) {
      const int a = __ffs(bmask) - 1;
      bmask &= bmask - 1;
      const int b = bmask ? (__ffs(bmask) - 1) : 32;
      const int dcur = __shfl(dv, a);
      float r0 = 0.0f, r1 = 0.0f;
      #pragma unroll
      for (int q = 0; q < 16; ++q) {
        const int row = (q & 3) + 8 * (q >> 2) + 4 * g;   // verified 32x32 C/D row map
        const bool in = (row >= a) && (row < b);
        r0 += in ? mv0[q] : 0.0f;
        r1 += in ? mv1[q] : 0.0f;
      }
      r0 += __shfl_xor(r0, 32);
      r1 += __shfl_xor(r1, 32);
      if (g == 0) {
        atomicAdd(agg + (size_t)dcur * F + lr,      r0);
        atomicAdd(agg + (size_t)dcur * F + 32 + lr, r1);
      }
    }
  }
}

__global__ void k_update(float4* __restrict__ agg4, const float* __restrict__ gam,
                         const float* __restrict__ bet, const float* __restrict__ mu,
                         const float* __restrict__ var, float4* __restrict__ h4,
                         ushort4* __restrict__ hb4, int layer) {
  int i = blockIdx.x * 256 + threadIdx.x;     // NN*F/4 = 800000
  if (i >= NN * F / 4) return;
  int c4 = (i * 4) & 63;
  float4 G = *(const float4*)(gam + layer * F + c4);
  float4 B = *(const float4*)(bet + layer * F + c4);
  float4 M = *(const float4*)(mu  + layer * F + c4);
  float4 V = *(const float4*)(var + layer * F + c4);
  float4 a = agg4[i];
  float4 h = h4[i];
  float4 o;
  float scx = G.x * rsqrtf(V.x + BN_EPS), scy = G.y * rsqrtf(V.y + BN_EPS);
  float scz = G.z * rsqrtf(V.z + BN_EPS), scw = G.w * rsqrtf(V.w + BN_EPS);
  o.x = fmaxf(a.x * scx + (B.x - M.x * scx) + h.x, 0.0f);
  o.y = fmaxf(a.y * scy + (B.y - M.y * scy) + h.y, 0.0f);
  o.z = fmaxf(a.z * scz + (B.z - M.z * scz) + h.z, 0.0f);
  o.w = fmaxf(a.w * scw + (B.w - M.w * scw) + h.w, 0.0f);
  agg4[i] = make_float4(0.f, 0.f, 0.f, 0.f);   // pre-zero for next layer
  h4[i] = o;
  union { bf16_t h[4]; ushort4 u; } pk;
  pk.h[0] = (bf16_t)o.x; pk.h[1] = (bf16_t)o.y; pk.h[2] = (bf16_t)o.z; pk.h[3] = (bf16_t)o.w;
  hb4[i] = pk.u;
}

__device__ __forceinline__ int lowb(const int* a, int n, int v) {
  int lo = 0, hi = n;
  while (lo < hi) { int mid = (lo + hi) >> 1; if (a[mid] < v) lo = mid + 1; else hi = mid; }
  return lo;
}

// final layer fused: pool = mean over relu(BN(agg) + h32), then 2-layer MLP
__global__ void k_pool_mlp(const float* __restrict__ agg, const float* __restrict__ h32,
                           const float* __restrict__ gam, const float* __restrict__ bet,
                           const float* __restrict__ mu, const float* __restrict__ var,
                           const int* __restrict__ batch,
                           const float* __restrict__ W1, const float* __restrict__ b1,
                           const float* __restrict__ W2, const float* __restrict__ b2,
                           float* __restrict__ out) {
  __shared__ float pooled[F];
  __shared__ float ps[HF];
  __shared__ float red[HF];
  const int gph = blockIdx.x;
  const int t = threadIdx.x;   // 128 threads
  const int c = t & 63;
  const int lo = lowb(batch, NN, gph);
  const int hi = lowb(batch, NN, gph + 1);

  const int L = NCONV - 1;
  const float sc = gam[L * F + c] * rsqrtf(var[L * F + c] + BN_EPS);
  const float sh = bet[L * F + c] - mu[L * F + c] * sc;

  float s = 0.f;
  for (int i = lo + (t >> 6); i < hi; i += 2) {
    float v = agg[(size_t)i * F + c] * sc + sh + h32[(size_t)i * F + c];
    s += fmaxf(v, 0.0f);
  }
  ps[t] = s;
  __syncthreads();
  if (t < F) {
    float tot = ps[t] + ps[t + F];
    pooled[t] = tot / fmaxf((float)(hi - lo), 1.0f);
  }
  __syncthreads();

  float a = b1[t];
  for (int cc = 0; cc < F; ++cc) a += pooled[cc] * W1[cc * HF + t];
  a = fmaxf(a, 0.f);
  red[t] = a * W2[t];
  __syncthreads();
  for (int sdv = 64; sdv > 0; sdv >>= 1) {
    if (t < sdv) red[t] += red[t + sdv];
    __syncthreads();
  }
  if (t == 0) out[gph] = red[0] + b2[0];
}

extern "C" void kernel_launch(void* const* d_in, const int* in_sizes, int n_in,
                              void* d_out, int out_size, void* d_ws, size_t ws_size,
                              hipStream_t stream) {
  const int*   x    = (const int*)d_in[0];
  const int*   ei   = (const int*)d_in[1];
  const float* ea   = (const float*)d_in[2];
  const int*   batch= (const int*)d_in[3];
  const float* emb  = (const float*)d_in[4];
  const float* Wf   = (const float*)d_in[5];
  const float* bfb  = (const float*)d_in[6];
  const float* Ws   = (const float*)d_in[7];
  const float* bsb  = (const float*)d_in[8];
  const float* gam  = (const float*)d_in[9];
  const float* bet  = (const float*)d_in[10];
  const float* mu   = (const float*)d_in[11];
  const float* var  = (const float*)d_in[12];
  const float* W1   = (const float*)d_in[13];
  const float* b1   = (const float*)d_in[14];
  const float* W2   = (const float*)d_in[15];
  const float* b2   = (const float*)d_in[16];
  float* out = (float*)d_out;

  char* p = (char*)d_ws;
  auto take = [&](size_t bytes) { char* q = p; p += (bytes + 255) & ~(size_t)255; return q; };
  float*  h32  = (float*)take((size_t)NN * F * 4);
  bf16_t* hb   = (bf16_t*)take((size_t)NN * F * 2);
  float*  agg  = (float*)take((size_t)NN * F * 4);
  bf16_t* Wt   = (bf16_t*)take((size_t)NCONV * NC * ZIN * 2);
  int*    cnt  = (int*)take((size_t)NN * 4);
  int*    head = (int*)take((size_t)NN * 4);
  int*    bsum = (int*)take((size_t)128 * 4);
  int*    srcs = (int*)take((size_t)NE * 4);
  int*    dsts = (int*)take((size_t)NE * 4);
  bf16_t* eas  = (bf16_t*)take((size_t)NE * ED * 2);

  hipMemsetAsync(cnt, 0, (size_t)NN * 4, stream);
  k_embed_hist<<<(NN * F / 4 + 255) / 256, 256, 0, stream>>>(x, emb, (float4*)h32,
                                                             (ushort4*)hb, ei, cnt, (float4*)agg);
  k_wprep<<<(NCONV * ZIN * NC + 255) / 256, 256, 0, stream>>>(Wf, Ws, Wt);

  k_scanA<<<SCB, 512, 0, stream>>>(cnt, head, bsum);
  k_scanB<<<1, 128, 0, stream>>>(bsum);
  k_scatter_ea<<<NWG * 8, 256, 0, stream>>>(ei, head, bsum, ea, dsts, srcs, eas);

  const size_t smem = 40960;  // Bsh only
  hipFuncSetAttribute((const void*)k_edges, hipFuncAttributeMaxDynamicSharedMemorySize, (int)smem);

  for (int layer = 0; layer < NCONV; ++layer) {
    k_edges<<<NWG, 512, smem, stream>>>(srcs, dsts, eas, hb, Wt, bfb, bsb, agg, layer);
    if (layer < NCONV - 1)
      k_update<<<(NN * F / 4 + 255) / 256, 256, 0, stream>>>((float4*)agg, gam, bet, mu, var,
                                                             (float4*)h32, (ushort4*)hb, layer);
  }

  k_pool_mlp<<<NG, HF, 0, stream>>>(agg, h32, gam, bet, mu, var, batch, W1, b1, W2, b2, out);
}

// Round 15
// 624.661 us; speedup vs baseline: 1.0787x; 1.0787x over previous
//
#include <hip/hip_runtime.h>
#include <hip/hip_bf16.h>
#include <cstdint>

#define NN    50000
#define NE    1600000
#define NG    512
#define F     64        // ATOM_FEA
#define ED    32        // EDGE_DIM
#define ZIN   160       // 2F + ED
#define NC    128       // fused Wf|Ws output cols
#define HF    128       // H_FEA
#define NCONV 3
#define BN_EPS 1e-5f
#define NWG   (NE / 256)   // 6250 k_edges workgroups
#define NPX   (NN / 8)     // 6250 nodes per XCD partition
#define SCB   98           // scan blocks: 98*512 = 50176 >= NN

typedef __bf16 bf16_t;
typedef bf16_t bf16x8 __attribute__((ext_vector_type(8)));
typedef float  f32x16 __attribute__((ext_vector_type(16)));

__global__ void k_embed_hist(const int* __restrict__ x, const float* __restrict__ emb,
                             float4* __restrict__ h4, ushort4* __restrict__ hb4,
                             const int* __restrict__ ei, int* __restrict__ cnt,
                             float4* __restrict__ agg4) {
  int i = blockIdx.x * 256 + threadIdx.x;          // 800000 lanes
  if (i < NN * F / 4) {
    int node = i >> 4, c4 = (i * 4) & 63;
    float4 v = *(const float4*)(emb + x[node] * F + c4);
    h4[i] = v;
    union { bf16_t h[4]; ushort4 u; } pk;
    pk.h[0] = (bf16_t)v.x; pk.h[1] = (bf16_t)v.y; pk.h[2] = (bf16_t)v.z; pk.h[3] = (bf16_t)v.w;
    hb4[i] = pk.u;
    agg4[i] = make_float4(0.f, 0.f, 0.f, 0.f);     // replaces separate memset (covers poison)
  }
  if (i < NE / 2) {
    atomicAdd(&cnt[ei[NE + i]], 1);
    atomicAdd(&cnt[ei[NE + i + NE / 2]], 1);
  }
}

// Wt layout: pre-fragmented for 32x32x16 MFMA B-operand, per layer:
//   Wt[((l*10 + ks)*4 + n)*512 + lane*8 + idx]
//   lane: g=lane>>5, lr=lane&31; col c = n*32+lr; k = 16*ks + 4*g + 8*(idx>>2) + (idx&3)
__global__ void k_wprep(const float* __restrict__ Wf, const float* __restrict__ Ws,
                        bf16_t* __restrict__ Wt) {
  int i = blockIdx.x * 256 + threadIdx.x;  // NCONV*ZIN*NC = 61440
  if (i >= NCONV * ZIN * NC) return;
  int l = i / 20480, r = i % 20480;
  int ks = r / 2048, r2 = r % 2048;
  int n = r2 / 512, r3 = r2 % 512;
  int lane = r3 >> 3, idx = r3 & 7;
  int g = lane >> 5, lr = lane & 31;
  int c = n * 32 + lr;
  int k = 16 * ks + 4 * g + 8 * (idx >> 2) + (idx & 3);
  float v = (c < F) ? Wf[(l * ZIN + k) * F + c] : Ws[(l * ZIN + k) * F + (c - F)];
  Wt[i] = (bf16_t)v;
}

// scan phase A: per-block exclusive scan (512 nodes/block) + block total
__global__ void k_scanA(const int* __restrict__ cnt, int* __restrict__ head,
                        int* __restrict__ bsum) {
  __shared__ int ts[512];
  const int b = blockIdx.x, t = threadIdx.x, i = b * 512 + t;
  int v = (i < NN) ? cnt[i] : 0;
  ts[t] = v;
  __syncthreads();
  for (int d = 1; d < 512; d <<= 1) {
    int xv = (t >= d) ? ts[t - d] : 0;
    __syncthreads();
    ts[t] += xv;
    __syncthreads();
  }
  if (i < NN) head[i] = ts[t] - v;       // block-local exclusive prefix
  if (t == 511) bsum[b] = ts[t];         // block total
}

// scan phase B: exclusive scan of the 98 block totals (in place)
__global__ void k_scanB(int* __restrict__ bsum) {
  __shared__ int ts[128];
  const int t = threadIdx.x;
  int v = (t < SCB) ? bsum[t] : 0;
  ts[t] = v;
  __syncthreads();
  for (int d = 1; d < 128; d <<= 1) {
    int xv = (t >= d) ? ts[t - d] : 0;
    __syncthreads();
    ts[t] += xv;
    __syncthreads();
  }
  if (t < SCB) bsum[t] = ts[t] - v;
}

// XCD-partitioned permutation scatter (R13's proven form): block b covers edge-chunk b>>3,
// accepts only edges whose dst is owned by XCD b&7 (round-robin blockIdx->XCD). All writers
// of any dsts/so/head line live on ONE XCD -> no partial-line write amplification.
// (R14 lesson: TCC lines are 128B; scattered 64B eas rows DO amplify -> keep gather split.)
__global__ void k_scatter_idx(const int* __restrict__ ei, int* __restrict__ head,
                              const int* __restrict__ bsum,
                              int* __restrict__ dsts, int2* __restrict__ so) {
  const int xcd = blockIdx.x & 7;
  const int e   = (blockIdx.x >> 3) * 256 + threadIdx.x;
  const int d   = ei[NE + e];
  if (d / NPX != xcd) return;
  const int p = atomicAdd(&head[d], 1) + bsum[d >> 9];
  dsts[p] = d;
  so[p] = make_int2(ei[e], e);
}

// gather ea rows (full-line random reads, no RMW) -> fully coalesced srcs/eas writes
__global__ void k_ea_gather(const int2* __restrict__ so, const float* __restrict__ ea,
                            int* __restrict__ srcs, bf16_t* __restrict__ eas) {
  int p = blockIdx.x * 256 + threadIdx.x;
  if (p >= NE) return;
  int2 v = so[p];
  srcs[p] = v.x;
  const float* pa = ea + (size_t)v.y * ED;
  bf16_t* pe = eas + (size_t)p * ED;
  #pragma unroll
  for (int q = 0; q < ED; q += 8) {
    float4 x0 = *(const float4*)(pa + q), x1 = *(const float4*)(pa + q + 4);
    union { bf16_t h[8]; uint4 u; } pk;
    pk.h[0] = (bf16_t)x0.x; pk.h[1] = (bf16_t)x0.y; pk.h[2] = (bf16_t)x0.z; pk.h[3] = (bf16_t)x0.w;
    pk.h[4] = (bf16_t)x1.x; pk.h[5] = (bf16_t)x1.y; pk.h[6] = (bf16_t)x1.z; pk.h[7] = (bf16_t)x1.w;
    *(uint4*)(pe + q) = pk.u;
  }
}

// 512 threads, 8 waves, 256 edges/block (32 edge-rows per wave) — R10/R13's proven structure.
// Registers: ~60 arch VGPR + 64 AGPR acc = ~124/thread -> 2 blocks/CU is the structural ceiling
// (R4 & R11 both proved forcing 6 waves/EU spills to scratch: WRITE_SIZE 0.5-3.4 GB).
// LDS: Bsh 40960 only. One barrier. Epilogue + segmented reduction fully in registers.
__launch_bounds__(512, 4)
__global__ void k_edges(const int* __restrict__ srcs, const int* __restrict__ dsts,
                        const bf16_t* __restrict__ eas, const bf16_t* __restrict__ hb,
                        const bf16_t* __restrict__ Wt,
                        const float* __restrict__ bfv, const float* __restrict__ bsv,
                        float* __restrict__ agg, int layer) {
  extern __shared__ char smem[];
  bf16_t* Bsh = (bf16_t*)smem;                       // [20480] pre-fragmented W

  const int tid = threadIdx.x;

  // bijective XCD-chunked swizzle: consecutive work -> same XCD (sorted-dst L2 locality)
  // NWG = 6250 = 8*781 + 2 -> q=781, r=2
  const int orig = blockIdx.x;
  const int xcd  = orig & 7;
  const int wg   = ((xcd < 2) ? xcd * 782 : 2 * 782 + (xcd - 2) * 781) + (orig >> 3);
  const int e0   = wg * 256;

  const int w  = tid >> 6;
  const int l  = tid & 63;
  const int lr = l & 31;
  const int g  = l >> 5;
  const int e  = w * 32 + lr;

  // long-latency loads first
  const int dv = dsts[e0 + e];
  const int sv = srcs[e0 + e];

  // per-lane bias values (folded into acc init via MFMA C-in)
  const float* bfl = bfv + layer * F;
  const float* bsl = bsv + layer * F;
  const float b0 = bfl[lr], b1 = bfl[lr + 32];
  const float s0b = bsl[lr], s1b = bsl[lr + 32];

  // gather A-fragments straight from global (fragment layout: lane=row, 8B strided by g-half)
  const char* dp = (const char*)(hb + (size_t)dv * F);
  const char* sp = (const char*)(hb + (size_t)sv * F);
  const char* ep = (const char*)(eas + (size_t)(e0 + e) * ED);
  uint2 dq[8], sq[8], eq[4];
  #pragma unroll
  for (int j = 0; j < 8; ++j) dq[j] = *(const uint2*)(dp + (2 * j + g) * 8);
  #pragma unroll
  for (int j = 0; j < 8; ++j) sq[j] = *(const uint2*)(sp + (2 * j + g) * 8);
  #pragma unroll
  for (int j = 0; j < 4; ++j) eq[j] = *(const uint2*)(ep + (2 * j + g) * 8);

  // stage B: 40960 B = 2560 uint4, 5 per thread
  {
    const uint4* Wg = (const uint4*)(Wt + (size_t)layer * NC * ZIN);
    uint4 breg[5];
    #pragma unroll
    for (int t = 0; t < 5; ++t) breg[t] = Wg[tid + t * 512];
    uint4* Bv = (uint4*)Bsh;
    #pragma unroll
    for (int t = 0; t < 5; ++t) Bv[tid + t * 512] = breg[t];
  }
  __syncthreads();   // the ONLY barrier: Bsh visible to all waves

  f32x16 acc[4];
  #pragma unroll
  for (int q = 0; q < 16; ++q) { acc[0][q] = b0; acc[1][q] = b1; acc[2][q] = s0b; acc[3][q] = s1b; }

  // independent-wave regime post-barrier -> setprio around MFMA cluster
  __builtin_amdgcn_s_setprio(1);
  #pragma unroll
  for (int ks = 0; ks < 10; ++ks) {
    union { uint2 u[2]; bf16x8 v; } a;
    a.u[0] = (ks < 4) ? dq[2 * ks]     : (ks < 8) ? sq[2 * (ks - 4)]     : eq[2 * (ks - 8)];
    a.u[1] = (ks < 4) ? dq[2 * ks + 1] : (ks < 8) ? sq[2 * (ks - 4) + 1] : eq[2 * (ks - 8) + 1];
    #pragma unroll
    for (int n = 0; n < 4; ++n) {
      bf16x8 b = *(const bf16x8*)(Bsh + ((ks * 4 + n) * 64 + l) * 8);  // ds_read_b128, stride-1
      acc[n] = __builtin_amdgcn_mfma_f32_32x32x16_bf16(a.v, b, acc[n], 0, 0, 0);
    }
  }
  __builtin_amdgcn_s_setprio(0);

  // epilogue in registers: mv0[q] = m[row(q,g)][lr], mv1[q] = m[row(q,g)][32+lr]
  const float L2E = 1.4426950408889634f, LN2 = 0.6931471805599453f;
  float mv0[16], mv1[16];
  #pragma unroll
  for (int q = 0; q < 16; ++q) {
    float f0 = acc[0][q], f1 = acc[1][q];
    float s2a = acc[2][q], s2c = acc[3][q];
    float sg0 = __builtin_amdgcn_rcpf(1.0f + __builtin_amdgcn_exp2f(-f0 * L2E));
    float sg1 = __builtin_amdgcn_rcpf(1.0f + __builtin_amdgcn_exp2f(-f1 * L2E));
    float sp0 = fmaxf(s2a, 0.0f) + __builtin_amdgcn_logf(1.0f + __builtin_amdgcn_exp2f(-fabsf(s2a) * L2E)) * LN2;
    float sp1 = fmaxf(s2c, 0.0f) + __builtin_amdgcn_logf(1.0f + __builtin_amdgcn_exp2f(-fabsf(s2c) * L2E)) * LN2;
    mv0[q] = sg0 * sp0;
    mv1[q] = sg1 * sp1;
  }

  // in-register segmented reduction over sorted-dst runs within this wave's 32-row window
  {
    const int dvp = __shfl(dv, l - 1);   // previous row's dst (lr>0 only)
    uint32_t bmask = ((uint32_t)__ballot(lr > 0 && dv != dvp)) | 1u;
    while (bmask) {
      const int a = __ffs(bmask) - 1;
      bmask &= bmask - 1;
      const int b = bmask ? (__ffs(bmask) - 1) : 32;
      const int dcur = __shfl(dv, a);
      float r0 = 0.0f, r1 = 0.0f;
      #pragma unroll
      for (int q = 0; q < 16; ++q) {
        const int row = (q & 3) + 8 * (q >> 2) + 4 * g;   // verified 32x32 C/D row map
        const bool in = (row >= a) && (row < b);
        r0 += in ? mv0[q] : 0.0f;
        r1 += in ? mv1[q] : 0.0f;
      }
      r0 += __shfl_xor(r0, 32);
      r1 += __shfl_xor(r1, 32);
      if (g == 0) {
        atomicAdd(agg + (size_t)dcur * F + lr,      r0);
        atomicAdd(agg + (size_t)dcur * F + 32 + lr, r1);
      }
    }
  }
}

__global__ void k_update(float4* __restrict__ agg4, const float* __restrict__ gam,
                         const float* __restrict__ bet, const float* __restrict__ mu,
                         const float* __restrict__ var, float4* __restrict__ h4,
                         ushort4* __restrict__ hb4, int layer) {
  int i = blockIdx.x * 256 + threadIdx.x;     // NN*F/4 = 800000
  if (i >= NN * F / 4) return;
  int c4 = (i * 4) & 63;
  float4 G = *(const float4*)(gam + layer * F + c4);
  float4 B = *(const float4*)(bet + layer * F + c4);
  float4 M = *(const float4*)(mu  + layer * F + c4);
  float4 V = *(const float4*)(var + layer * F + c4);
  float4 a = agg4[i];
  float4 h = h4[i];
  float4 o;
  float scx = G.x * rsqrtf(V.x + BN_EPS), scy = G.y * rsqrtf(V.y + BN_EPS);
  float scz = G.z * rsqrtf(V.z + BN_EPS), scw = G.w * rsqrtf(V.w + BN_EPS);
  o.x = fmaxf(a.x * scx + (B.x - M.x * scx) + h.x, 0.0f);
  o.y = fmaxf(a.y * scy + (B.y - M.y * scy) + h.y, 0.0f);
  o.z = fmaxf(a.z * scz + (B.z - M.z * scz) + h.z, 0.0f);
  o.w = fmaxf(a.w * scw + (B.w - M.w * scw) + h.w, 0.0f);
  agg4[i] = make_float4(0.f, 0.f, 0.f, 0.f);   // pre-zero for next layer
  h4[i] = o;
  union { bf16_t h[4]; ushort4 u; } pk;
  pk.h[0] = (bf16_t)o.x; pk.h[1] = (bf16_t)o.y; pk.h[2] = (bf16_t)o.z; pk.h[3] = (bf16_t)o.w;
  hb4[i] = pk.u;
}

__device__ __forceinline__ int lowb(const int* a, int n, int v) {
  int lo = 0, hi = n;
  while (lo < hi) { int mid = (lo + hi) >> 1; if (a[mid] < v) lo = mid + 1; else hi = mid; }
  return lo;
}

// final layer fused: pool = mean over relu(BN(agg) + h32), then 2-layer MLP
__global__ void k_pool_mlp(const float* __restrict__ agg, const float* __restrict__ h32,
                           const float* __restrict__ gam, const float* __restrict__ bet,
                           const float* __restrict__ mu, const float* __restrict__ var,
                           const int* __restrict__ batch,
                           const float* __restrict__ W1, const float* __restrict__ b1,
                           const float* __restrict__ W2, const float* __restrict__ b2,
                           float* __restrict__ out) {
  __shared__ float pooled[F];
  __shared__ float ps[HF];
  __shared__ float red[HF];
  const int gph = blockIdx.x;
  const int t = threadIdx.x;   // 128 threads
  const int c = t & 63;
  const int lo = lowb(batch, NN, gph);
  const int hi = lowb(batch, NN, gph + 1);

  const int L = NCONV - 1;
  const float sc = gam[L * F + c] * rsqrtf(var[L * F + c] + BN_EPS);
  const float sh = bet[L * F + c] - mu[L * F + c] * sc;

  float s = 0.f;
  for (int i = lo + (t >> 6); i < hi; i += 2) {
    float v = agg[(size_t)i * F + c] * sc + sh + h32[(size_t)i * F + c];
    s += fmaxf(v, 0.0f);
  }
  ps[t] = s;
  __syncthreads();
  if (t < F) {
    float tot = ps[t] + ps[t + F];
    pooled[t] = tot / fmaxf((float)(hi - lo), 1.0f);
  }
  __syncthreads();

  float a = b1[t];
  for (int cc = 0; cc < F; ++cc) a += pooled[cc] * W1[cc * HF + t];
  a = fmaxf(a, 0.f);
  red[t] = a * W2[t];
  __syncthreads();
  for (int sdv = 64; sdv > 0; sdv >>= 1) {
    if (t < sdv) red[t] += red[t + sdv];
    __syncthreads();
  }
  if (t == 0) out[gph] = red[0] + b2[0];
}

extern "C" void kernel_launch(void* const* d_in, const int* in_sizes, int n_in,
                              void* d_out, int out_size, void* d_ws, size_t ws_size,
                              hipStream_t stream) {
  const int*   x    = (const int*)d_in[0];
  const int*   ei   = (const int*)d_in[1];
  const float* ea   = (const float*)d_in[2];
  const int*   batch= (const int*)d_in[3];
  const float* emb  = (const float*)d_in[4];
  const float* Wf   = (const float*)d_in[5];
  const float* bfb  = (const float*)d_in[6];
  const float* Ws   = (const float*)d_in[7];
  const float* bsb  = (const float*)d_in[8];
  const float* gam  = (const float*)d_in[9];
  const float* bet  = (const float*)d_in[10];
  const float* mu   = (const float*)d_in[11];
  const float* var  = (const float*)d_in[12];
  const float* W1   = (const float*)d_in[13];
  const float* b1   = (const float*)d_in[14];
  const float* W2   = (const float*)d_in[15];
  const float* b2   = (const float*)d_in[16];
  float* out = (float*)d_out;

  char* p = (char*)d_ws;
  auto take = [&](size_t bytes) { char* q = p; p += (bytes + 255) & ~(size_t)255; return q; };
  float*  h32  = (float*)take((size_t)NN * F * 4);
  bf16_t* hb   = (bf16_t*)take((size_t)NN * F * 2);
  float*  agg  = (float*)take((size_t)NN * F * 4);
  bf16_t* Wt   = (bf16_t*)take((size_t)NCONV * NC * ZIN * 2);
  int*    cnt  = (int*)take((size_t)NN * 4);
  int*    head = (int*)take((size_t)NN * 4);
  int*    bsum = (int*)take((size_t)128 * 4);
  int*    srcs = (int*)take((size_t)NE * 4);
  int*    dsts = (int*)take((size_t)NE * 4);
  bf16_t* eas  = (bf16_t*)take((size_t)NE * ED * 2);
  int2*   so   = (int2*)take((size_t)NE * 8);

  hipMemsetAsync(cnt, 0, (size_t)NN * 4, stream);
  k_embed_hist<<<(NN * F / 4 + 255) / 256, 256, 0, stream>>>(x, emb, (float4*)h32,
                                                             (ushort4*)hb, ei, cnt, (float4*)agg);
  k_wprep<<<(NCONV * ZIN * NC + 255) / 256, 256, 0, stream>>>(Wf, Ws, Wt);

  k_scanA<<<SCB, 512, 0, stream>>>(cnt, head, bsum);
  k_scanB<<<1, 128, 0, stream>>>(bsum);
  k_scatter_idx<<<NWG * 8, 256, 0, stream>>>(ei, head, bsum, dsts, so);
  k_ea_gather<<<(NE + 255) / 256, 256, 0, stream>>>(so, ea, srcs, eas);

  const size_t smem = 40960;  // Bsh only
  hipFuncSetAttribute((const void*)k_edges, hipFuncAttributeMaxDynamicSharedMemorySize, (int)smem);

  for (int layer = 0; layer < NCONV; ++layer) {
    k_edges<<<NWG, 512, smem, stream>>>(srcs, dsts, eas, hb, Wt, bfb, bsb, agg, layer);
    if (layer < NCONV - 1)
      k_update<<<(NN * F / 4 + 255) / 256, 256, 0, stream>>>((float4*)agg, gam, bet, mu, var,
                                                             (float4*)h32, (ushort4*)hb, layer);
  }

  k_pool_mlp<<<NG, HF, 0, stream>>>(agg, h32, gam, bet, mu, var, batch, W1, b1, W2, b2, out);
}

// Round 16
// 589.715 us; speedup vs baseline: 1.1426x; 1.0593x over previous
//
#include <hip/hip_runtime.h>
#include <hip/hip_bf16.h>
#include <cstdint>

#define NN    50000
#define NE    1600000
#define NG    512
#define F     64        // ATOM_FEA
#define ED    32        // EDGE_DIM
#define ZIN   160       // 2F + ED
#define NC    128       // fused Wf|Ws output cols
#define HF    128       // H_FEA
#define NCONV 3
#define BN_EPS 1e-5f
#define NWG   (NE / 256)   // 6250 k_edges workgroups
#define NPX   (NN / 8)     // 6250 nodes per XCD partition
#define SCB   98           // scan blocks: 98*512 = 50176 >= NN

typedef __bf16 bf16_t;
typedef bf16_t bf16x8 __attribute__((ext_vector_type(8)));
typedef float  f32x16 __attribute__((ext_vector_type(16)));

__global__ void k_embed_hist(const int* __restrict__ x, const float* __restrict__ emb,
                             float4* __restrict__ h4, ushort4* __restrict__ hb4,
                             const int* __restrict__ ei, int* __restrict__ cnt,
                             float4* __restrict__ agg4) {
  int i = blockIdx.x * 256 + threadIdx.x;          // 800000 lanes
  if (i < NN * F / 4) {
    int node = i >> 4, c4 = (i * 4) & 63;
    float4 v = *(const float4*)(emb + x[node] * F + c4);
    h4[i] = v;
    union { bf16_t h[4]; ushort4 u; } pk;
    pk.h[0] = (bf16_t)v.x; pk.h[1] = (bf16_t)v.y; pk.h[2] = (bf16_t)v.z; pk.h[3] = (bf16_t)v.w;
    hb4[i] = pk.u;
    agg4[i] = make_float4(0.f, 0.f, 0.f, 0.f);     // replaces separate memset (covers poison)
  }
  if (i < NE / 2) {
    atomicAdd(&cnt[ei[NE + i]], 1);
    atomicAdd(&cnt[ei[NE + i + NE / 2]], 1);
  }
}

// Wt layout: pre-fragmented for 32x32x16 MFMA B-operand, per layer:
//   Wt[((l*10 + ks)*4 + n)*512 + lane*8 + idx]
//   lane: g=lane>>5, lr=lane&31; col c = n*32+lr.
// CONTIGUOUS k-permutation (R16): chosen so the A-side gather is 16B-contiguous per lane.
//   ks 0-3 (h_dst): k = g*32 + ks*8 + idx
//   ks 4-7 (h_src): k = 64 + g*32 + (ks-4)*8 + idx
//   ks 8-9 (e):     k = 128 + g*16 + (ks-8)*8 + idx
// Any k-permutation is valid as long as A and B agree (dot product is permutation-invariant).
__global__ void k_wprep(const float* __restrict__ Wf, const float* __restrict__ Ws,
                        bf16_t* __restrict__ Wt) {
  int i = blockIdx.x * 256 + threadIdx.x;  // NCONV*ZIN*NC = 61440
  if (i >= NCONV * ZIN * NC) return;
  int l = i / 20480, r = i % 20480;
  int ks = r / 2048, r2 = r % 2048;
  int n = r2 / 512, r3 = r2 % 512;
  int lane = r3 >> 3, idx = r3 & 7;
  int g = lane >> 5, lr = lane & 31;
  int c = n * 32 + lr;
  int k;
  if (ks < 4)      k = g * 32 + ks * 8 + idx;
  else if (ks < 8) k = 64 + g * 32 + (ks - 4) * 8 + idx;
  else             k = 128 + g * 16 + (ks - 8) * 8 + idx;
  float v = (c < F) ? Wf[(l * ZIN + k) * F + c] : Ws[(l * ZIN + k) * F + (c - F)];
  Wt[i] = (bf16_t)v;
}

// scan phase A: per-block exclusive scan (512 nodes/block) + block total
__global__ void k_scanA(const int* __restrict__ cnt, int* __restrict__ head,
                        int* __restrict__ bsum) {
  __shared__ int ts[512];
  const int b = blockIdx.x, t = threadIdx.x, i = b * 512 + t;
  int v = (i < NN) ? cnt[i] : 0;
  ts[t] = v;
  __syncthreads();
  for (int d = 1; d < 512; d <<= 1) {
    int xv = (t >= d) ? ts[t - d] : 0;
    __syncthreads();
    ts[t] += xv;
    __syncthreads();
  }
  if (i < NN) head[i] = ts[t] - v;       // block-local exclusive prefix
  if (t == 511) bsum[b] = ts[t];         // block total
}

// scan phase B: exclusive scan of the 98 block totals (in place)
__global__ void k_scanB(int* __restrict__ bsum) {
  __shared__ int ts[128];
  const int t = threadIdx.x;
  int v = (t < SCB) ? bsum[t] : 0;
  ts[t] = v;
  __syncthreads();
  for (int d = 1; d < 128; d <<= 1) {
    int xv = (t >= d) ? ts[t - d] : 0;
    __syncthreads();
    ts[t] += xv;
    __syncthreads();
  }
  if (t < SCB) bsum[t] = ts[t] - v;
}

// XCD-partitioned permutation scatter (R13's proven form): block b covers edge-chunk b>>3,
// accepts only edges whose dst is owned by XCD b&7 (round-robin blockIdx->XCD). All writers
// of any dsts/so/head line live on ONE XCD -> no partial-line write amplification.
// (R14 lesson: TCC lines are 128B; scattered 64B eas rows DO amplify -> keep gather split.)
__global__ void k_scatter_idx(const int* __restrict__ ei, int* __restrict__ head,
                              const int* __restrict__ bsum,
                              int* __restrict__ dsts, int2* __restrict__ so) {
  const int xcd = blockIdx.x & 7;
  const int e   = (blockIdx.x >> 3) * 256 + threadIdx.x;
  const int d   = ei[NE + e];
  if (d / NPX != xcd) return;
  const int p = atomicAdd(&head[d], 1) + bsum[d >> 9];
  dsts[p] = d;
  so[p] = make_int2(ei[e], e);
}

// gather ea rows (full-line random reads, no RMW) -> fully coalesced srcs/eas writes
__global__ void k_ea_gather(const int2* __restrict__ so, const float* __restrict__ ea,
                            int* __restrict__ srcs, bf16_t* __restrict__ eas) {
  int p = blockIdx.x * 256 + threadIdx.x;
  if (p >= NE) return;
  int2 v = so[p];
  srcs[p] = v.x;
  const float* pa = ea + (size_t)v.y * ED;
  bf16_t* pe = eas + (size_t)p * ED;
  #pragma unroll
  for (int q = 0; q < ED; q += 8) {
    float4 x0 = *(const float4*)(pa + q), x1 = *(const float4*)(pa + q + 4);
    union { bf16_t h[8]; uint4 u; } pk;
    pk.h[0] = (bf16_t)x0.x; pk.h[1] = (bf16_t)x0.y; pk.h[2] = (bf16_t)x0.z; pk.h[3] = (bf16_t)x0.w;
    pk.h[4] = (bf16_t)x1.x; pk.h[5] = (bf16_t)x1.y; pk.h[6] = (bf16_t)x1.z; pk.h[7] = (bf16_t)x1.w;
    *(uint4*)(pe + q) = pk.u;
  }
}

// 512 threads, 8 waves, 256 edges/block (32 edge-rows per wave) — R10/R13's proven structure
// + R16 contiguous-k A-gather: 10x global_load_dwordx4 per lane (was 20x dwordx2),
// fragment ks == one uint4 register (selection logic gone).
// Registers: ~60 arch VGPR + 64 AGPR acc -> 2 blocks/CU is the structural ceiling
// (R4 & R11 both proved forcing 6 waves/EU spills to scratch: WRITE_SIZE 0.5-3.4 GB).
// LDS: Bsh 40960 only. One barrier. Epilogue + segmented reduction fully in registers.
__launch_bounds__(512, 4)
__global__ void k_edges(const int* __restrict__ srcs, const int* __restrict__ dsts,
                        const bf16_t* __restrict__ eas, const bf16_t* __restrict__ hb,
                        const bf16_t* __restrict__ Wt,
                        const float* __restrict__ bfv, const float* __restrict__ bsv,
                        float* __restrict__ agg, int layer) {
  extern __shared__ char smem[];
  bf16_t* Bsh = (bf16_t*)smem;                       // [20480] pre-fragmented W

  const int tid = threadIdx.x;

  // bijective XCD-chunked swizzle: consecutive work -> same XCD (sorted-dst L2 locality)
  // NWG = 6250 = 8*781 + 2 -> q=781, r=2
  const int orig = blockIdx.x;
  const int xcd  = orig & 7;
  const int wg   = ((xcd < 2) ? xcd * 782 : 2 * 782 + (xcd - 2) * 781) + (orig >> 3);
  const int e0   = wg * 256;

  const int w  = tid >> 6;
  const int l  = tid & 63;
  const int lr = l & 31;
  const int g  = l >> 5;
  const int e  = w * 32 + lr;

  // long-latency loads first
  const int dv = dsts[e0 + e];
  const int sv = srcs[e0 + e];

  // per-lane bias values (folded into acc init via MFMA C-in)
  const float* bfl = bfv + layer * F;
  const float* bsl = bsv + layer * F;
  const float b0 = bfl[lr], b1 = bfl[lr + 32];
  const float s0b = bsl[lr], s1b = bsl[lr + 32];

  // A-gather, contiguous-k layout: lane's g-half owns k[g*32,(g+1)*32) of each 64-elem row
  // (e: k[g*16,(g+1)*16)) -> 16B-contiguous chunks; fragment ks = frag[ks] directly.
  uint4 frag[10];
  {
    const char* dp = (const char*)(hb + (size_t)dv * F) + g * 64;
    const char* sp = (const char*)(hb + (size_t)sv * F) + g * 64;
    const char* ep = (const char*)(eas + (size_t)(e0 + e) * ED) + g * 32;
    #pragma unroll
    for (int j = 0; j < 4; ++j) frag[j] = *(const uint4*)(dp + j * 16);
    #pragma unroll
    for (int j = 0; j < 4; ++j) frag[4 + j] = *(const uint4*)(sp + j * 16);
    frag[8] = *(const uint4*)(ep);
    frag[9] = *(const uint4*)(ep + 16);
  }

  // stage B: 40960 B = 2560 uint4, 5 per thread
  {
    const uint4* Wg = (const uint4*)(Wt + (size_t)layer * NC * ZIN);
    uint4 breg[5];
    #pragma unroll
    for (int t = 0; t < 5; ++t) breg[t] = Wg[tid + t * 512];
    uint4* Bv = (uint4*)Bsh;
    #pragma unroll
    for (int t = 0; t < 5; ++t) Bv[tid + t * 512] = breg[t];
  }
  __syncthreads();   // the ONLY barrier: Bsh visible to all waves

  f32x16 acc[4];
  #pragma unroll
  for (int q = 0; q < 16; ++q) { acc[0][q] = b0; acc[1][q] = b1; acc[2][q] = s0b; acc[3][q] = s1b; }

  // independent-wave regime post-barrier -> setprio around MFMA cluster
  __builtin_amdgcn_s_setprio(1);
  #pragma unroll
  for (int ks = 0; ks < 10; ++ks) {
    union { uint4 u; bf16x8 v; } a;
    a.u = frag[ks];
    #pragma unroll
    for (int n = 0; n < 4; ++n) {
      bf16x8 b = *(const bf16x8*)(Bsh + ((ks * 4 + n) * 64 + l) * 8);  // ds_read_b128, stride-1
      acc[n] = __builtin_amdgcn_mfma_f32_32x32x16_bf16(a.v, b, acc[n], 0, 0, 0);
    }
  }
  __builtin_amdgcn_s_setprio(0);

  // epilogue in registers: mv0[q] = m[row(q,g)][lr], mv1[q] = m[row(q,g)][32+lr]
  const float L2E = 1.4426950408889634f, LN2 = 0.6931471805599453f;
  float mv0[16], mv1[16];
  #pragma unroll
  for (int q = 0; q < 16; ++q) {
    float f0 = acc[0][q], f1 = acc[1][q];
    float s2a = acc[2][q], s2c = acc[3][q];
    float sg0 = __builtin_amdgcn_rcpf(1.0f + __builtin_amdgcn_exp2f(-f0 * L2E));
    float sg1 = __builtin_amdgcn_rcpf(1.0f + __builtin_amdgcn_exp2f(-f1 * L2E));
    float sp0 = fmaxf(s2a, 0.0f) + __builtin_amdgcn_logf(1.0f + __builtin_amdgcn_exp2f(-fabsf(s2a) * L2E)) * LN2;
    float sp1 = fmaxf(s2c, 0.0f) + __builtin_amdgcn_logf(1.0f + __builtin_amdgcn_exp2f(-fabsf(s2c) * L2E)) * LN2;
    mv0[q] = sg0 * sp0;
    mv1[q] = sg1 * sp1;
  }

  // in-register segmented reduction over sorted-dst runs within this wave's 32-row window
  {
    const int dvp = __shfl(dv, l - 1);   // previous row's dst (lr>0 only)
    uint32_t bmask = ((uint32_t)__ballot(lr > 0 && dv != dvp)) | 1u;
    while (bmask) {
      const int a = __ffs(bmask) - 1;
      bmask &= bmask - 1;
      const int b = bmask ? (__ffs(bmask) - 1) : 32;
      const int dcur = __shfl(dv, a);
      float r0 = 0.0f, r1 = 0.0f;
      #pragma unroll
      for (int q = 0; q < 16; ++q) {
        const int row = (q & 3) + 8 * (q >> 2) + 4 * g;   // verified 32x32 C/D row map
        const bool in = (row >= a) && (row < b);
        r0 += in ? mv0[q] : 0.0f;
        r1 += in ? mv1[q] : 0.0f;
      }
      r0 += __shfl_xor(r0, 32);
      r1 += __shfl_xor(r1, 32);
      if (g == 0) {
        atomicAdd(agg + (size_t)dcur * F + lr,      r0);
        atomicAdd(agg + (size_t)dcur * F + 32 + lr, r1);
      }
    }
  }
}

__global__ void k_update(float4* __restrict__ agg4, const float* __restrict__ gam,
                         const float* __restrict__ bet, const float* __restrict__ mu,
                         const float* __restrict__ var, float4* __restrict__ h4,
                         ushort4* __restrict__ hb4, int layer) {
  int i = blockIdx.x * 256 + threadIdx.x;     // NN*F/4 = 800000
  if (i >= NN * F / 4) return;
  int c4 = (i * 4) & 63;
  float4 G = *(const float4*)(gam + layer * F + c4);
  float4 B = *(const float4*)(bet + layer * F + c4);
  float4 M = *(const float4*)(mu  + layer * F + c4);
  float4 V = *(const float4*)(var + layer * F + c4);
  float4 a = agg4[i];
  float4 h = h4[i];
  float4 o;
  float scx = G.x * rsqrtf(V.x + BN_EPS), scy = G.y * rsqrtf(V.y + BN_EPS);
  float scz = G.z * rsqrtf(V.z + BN_EPS), scw = G.w * rsqrtf(V.w + BN_EPS);
  o.x = fmaxf(a.x * scx + (B.x - M.x * scx) + h.x, 0.0f);
  o.y = fmaxf(a.y * scy + (B.y - M.y * scy) + h.y, 0.0f);
  o.z = fmaxf(a.z * scz + (B.z - M.z * scz) + h.z, 0.0f);
  o.w = fmaxf(a.w * scw + (B.w - M.w * scw) + h.w, 0.0f);
  agg4[i] = make_float4(0.f, 0.f, 0.f, 0.f);   // pre-zero for next layer
  h4[i] = o;
  union { bf16_t h[4]; ushort4 u; } pk;
  pk.h[0] = (bf16_t)o.x; pk.h[1] = (bf16_t)o.y; pk.h[2] = (bf16_t)o.z; pk.h[3] = (bf16_t)o.w;
  hb4[i] = pk.u;
}

__device__ __forceinline__ int lowb(const int* a, int n, int v) {
  int lo = 0, hi = n;
  while (lo < hi) { int mid = (lo + hi) >> 1; if (a[mid] < v) lo = mid + 1; else hi = mid; }
  return lo;
}

// final layer fused: pool = mean over relu(BN(agg) + h32), then 2-layer MLP
__global__ void k_pool_mlp(const float* __restrict__ agg, const float* __restrict__ h32,
                           const float* __restrict__ gam, const float* __restrict__ bet,
                           const float* __restrict__ mu, const float* __restrict__ var,
                           const int* __restrict__ batch,
                           const float* __restrict__ W1, const float* __restrict__ b1,
                           const float* __restrict__ W2, const float* __restrict__ b2,
                           float* __restrict__ out) {
  __shared__ float pooled[F];
  __shared__ float ps[HF];
  __shared__ float red[HF];
  const int gph = blockIdx.x;
  const int t = threadIdx.x;   // 128 threads
  const int c = t & 63;
  const int lo = lowb(batch, NN, gph);
  const int hi = lowb(batch, NN, gph + 1);

  const int L = NCONV - 1;
  const float sc = gam[L * F + c] * rsqrtf(var[L * F + c] + BN_EPS);
  const float sh = bet[L * F + c] - mu[L * F + c] * sc;

  float s = 0.f;
  for (int i = lo + (t >> 6); i < hi; i += 2) {
    float v = agg[(size_t)i * F + c] * sc + sh + h32[(size_t)i * F + c];
    s += fmaxf(v, 0.0f);
  }
  ps[t] = s;
  __syncthreads();
  if (t < F) {
    float tot = ps[t] + ps[t + F];
    pooled[t] = tot / fmaxf((float)(hi - lo), 1.0f);
  }
  __syncthreads();

  float a = b1[t];
  for (int cc = 0; cc < F; ++cc) a += pooled[cc] * W1[cc * HF + t];
  a = fmaxf(a, 0.f);
  red[t] = a * W2[t];
  __syncthreads();
  for (int sdv = 64; sdv > 0; sdv >>= 1) {
    if (t < sdv) red[t] += red[t + sdv];
    __syncthreads();
  }
  if (t == 0) out[gph] = red[0] + b2[0];
}

extern "C" void kernel_launch(void* const* d_in, const int* in_sizes, int n_in,
                              void* d_out, int out_size, void* d_ws, size_t ws_size,
                              hipStream_t stream) {
  const int*   x    = (const int*)d_in[0];
  const int*   ei   = (const int*)d_in[1];
  const float* ea   = (const float*)d_in[2];
  const int*   batch= (const int*)d_in[3];
  const float* emb  = (const float*)d_in[4];
  const float* Wf   = (const float*)d_in[5];
  const float* bfb  = (const float*)d_in[6];
  const float* Ws   = (const float*)d_in[7];
  const float* bsb  = (const float*)d_in[8];
  const float* gam  = (const float*)d_in[9];
  const float* bet  = (const float*)d_in[10];
  const float* mu   = (const float*)d_in[11];
  const float* var  = (const float*)d_in[12];
  const float* W1   = (const float*)d_in[13];
  const float* b1   = (const float*)d_in[14];
  const float* W2   = (const float*)d_in[15];
  const float* b2   = (const float*)d_in[16];
  float* out = (float*)d_out;

  char* p = (char*)d_ws;
  auto take = [&](size_t bytes) { char* q = p; p += (bytes + 255) & ~(size_t)255; return q; };
  float*  h32  = (float*)take((size_t)NN * F * 4);
  bf16_t* hb   = (bf16_t*)take((size_t)NN * F * 2);
  float*  agg  = (float*)take((size_t)NN * F * 4);
  bf16_t* Wt   = (bf16_t*)take((size_t)NCONV * NC * ZIN * 2);
  int*    cnt  = (int*)take((size_t)NN * 4);
  int*    head = (int*)take((size_t)NN * 4);
  int*    bsum = (int*)take((size_t)128 * 4);
  int*    srcs = (int*)take((size_t)NE * 4);
  int*    dsts = (int*)take((size_t)NE * 4);
  bf16_t* eas  = (bf16_t*)take((size_t)NE * ED * 2);
  int2*   so   = (int2*)take((size_t)NE * 8);

  hipMemsetAsync(cnt, 0, (size_t)NN * 4, stream);
  k_embed_hist<<<(NN * F / 4 + 255) / 256, 256, 0, stream>>>(x, emb, (float4*)h32,
                                                             (ushort4*)hb, ei, cnt, (float4*)agg);
  k_wprep<<<(NCONV * ZIN * NC + 255) / 256, 256, 0, stream>>>(Wf, Ws, Wt);

  k_scanA<<<SCB, 512, 0, stream>>>(cnt, head, bsum);
  k_scanB<<<1, 128, 0, stream>>>(bsum);
  k_scatter_idx<<<NWG * 8, 256, 0, stream>>>(ei, head, bsum, dsts, so);
  k_ea_gather<<<(NE + 255) / 256, 256, 0, stream>>>(so, ea, srcs, eas);

  const size_t smem = 40960;  // Bsh only
  hipFuncSetAttribute((const void*)k_edges, hipFuncAttributeMaxDynamicSharedMemorySize, (int)smem);

  for (int layer = 0; layer < NCONV; ++layer) {
    k_edges<<<NWG, 512, smem, stream>>>(srcs, dsts, eas, hb, Wt, bfb, bsb, agg, layer);
    if (layer < NCONV - 1)
      k_update<<<(NN * F / 4 + 255) / 256, 256, 0, stream>>>((float4*)agg, gam, bet, mu, var,
                                                             (float4*)h32, (ushort4*)hb, layer);
  }

  k_pool_mlp<<<NG, HF, 0, stream>>>(agg, h32, gam, bet, mu, var, batch, W1, b1, W2, b2, out);
}

// Round 17
// 583.008 us; speedup vs baseline: 1.1558x; 1.0115x over previous
//
#include <hip/hip_runtime.h>
#include <hip/hip_bf16.h>
#include <cstdint>

#define NN    50000
#define NE    1600000
#define NG    512
#define F     64        // ATOM_FEA
#define ED    32        // EDGE_DIM
#define ZIN   160       // 2F + ED
#define NC    128       // fused Wf|Ws output cols
#define HF    128       // H_FEA
#define NCONV 3
#define BN_EPS 1e-5f
#define NWG   (NE / 256)   // 6250 k_edges workgroups
#define NPX   (NN / 8)     // 6250 nodes per XCD partition
#define SCB   98           // scan blocks: 98*512 = 50176 >= NN

typedef __bf16 bf16_t;
typedef bf16_t bf16x8 __attribute__((ext_vector_type(8)));
typedef float  f32x16 __attribute__((ext_vector_type(16)));

__global__ void k_embed_hist(const int* __restrict__ x, const float* __restrict__ emb,
                             float4* __restrict__ h4, ushort4* __restrict__ hb4,
                             const int* __restrict__ ei, int* __restrict__ cnt,
                             float4* __restrict__ agg4) {
  int i = blockIdx.x * 256 + threadIdx.x;          // 800000 lanes
  if (i < NN * F / 4) {
    int node = i >> 4, c4 = (i * 4) & 63;
    float4 v = *(const float4*)(emb + x[node] * F + c4);
    h4[i] = v;
    union { bf16_t h[4]; ushort4 u; } pk;
    pk.h[0] = (bf16_t)v.x; pk.h[1] = (bf16_t)v.y; pk.h[2] = (bf16_t)v.z; pk.h[3] = (bf16_t)v.w;
    hb4[i] = pk.u;
    agg4[i] = make_float4(0.f, 0.f, 0.f, 0.f);     // replaces separate memset (covers poison)
  }
  if (i < NE / 2) {
    atomicAdd(&cnt[ei[NE + i]], 1);
    atomicAdd(&cnt[ei[NE + i + NE / 2]], 1);
  }
}

// Wt layout: pre-fragmented for 32x32x16 MFMA B-operand, per layer:
//   Wt[((l*10 + ks)*4 + n)*512 + lane*8 + idx]
//   lane: g=lane>>5, lr=lane&31; col c = n*32+lr.
// CONTIGUOUS k-permutation (R16): A-side gather is 16B-contiguous per lane.
//   ks 0-3 (h_dst): k = g*32 + ks*8 + idx
//   ks 4-7 (h_src): k = 64 + g*32 + (ks-4)*8 + idx
//   ks 8-9 (e):     k = 128 + g*16 + (ks-8)*8 + idx
// Any k-permutation is valid as long as A and B agree (dot product is permutation-invariant).
__global__ void k_wprep(const float* __restrict__ Wf, const float* __restrict__ Ws,
                        bf16_t* __restrict__ Wt) {
  int i = blockIdx.x * 256 + threadIdx.x;  // NCONV*ZIN*NC = 61440
  if (i >= NCONV * ZIN * NC) return;
  int l = i / 20480, r = i % 20480;
  int ks = r / 2048, r2 = r % 2048;
  int n = r2 / 512, r3 = r2 % 512;
  int lane = r3 >> 3, idx = r3 & 7;
  int g = lane >> 5, lr = lane & 31;
  int c = n * 32 + lr;
  int k;
  if (ks < 4)      k = g * 32 + ks * 8 + idx;
  else if (ks < 8) k = 64 + g * 32 + (ks - 4) * 8 + idx;
  else             k = 128 + g * 16 + (ks - 8) * 8 + idx;
  float v = (c < F) ? Wf[(l * ZIN + k) * F + c] : Ws[(l * ZIN + k) * F + (c - F)];
  Wt[i] = (bf16_t)v;
}

// scan phase A: per-block exclusive scan (512 nodes/block) + block total
__global__ void k_scanA(const int* __restrict__ cnt, int* __restrict__ head,
                        int* __restrict__ bsum) {
  __shared__ int ts[512];
  const int b = blockIdx.x, t = threadIdx.x, i = b * 512 + t;
  int v = (i < NN) ? cnt[i] : 0;
  ts[t] = v;
  __syncthreads();
  for (int d = 1; d < 512; d <<= 1) {
    int xv = (t >= d) ? ts[t - d] : 0;
    __syncthreads();
    ts[t] += xv;
    __syncthreads();
  }
  if (i < NN) head[i] = ts[t] - v;       // block-local exclusive prefix
  if (t == 511) bsum[b] = ts[t];         // block total
}

// scan phase B: exclusive scan of the 98 block totals (in place)
__global__ void k_scanB(int* __restrict__ bsum) {
  __shared__ int ts[128];
  const int t = threadIdx.x;
  int v = (t < SCB) ? bsum[t] : 0;
  ts[t] = v;
  __syncthreads();
  for (int d = 1; d < 128; d <<= 1) {
    int xv = (t >= d) ? ts[t - d] : 0;
    __syncthreads();
    ts[t] += xv;
    __syncthreads();
  }
  if (t < SCB) bsum[t] = ts[t] - v;
}

// XCD-partitioned permutation scatter: block b covers edge-chunk b>>3, accepts only
// edges whose dst is owned by XCD b&7 (round-robin blockIdx->XCD). All writers of any
// output line live on ONE XCD -> no partial-line write amplification (R13 mechanism).
// R17: (dst,src) packed as int2 so k_edges does one 8B load instead of two 4B loads.
__global__ void k_scatter_idx(const int* __restrict__ ei, int* __restrict__ head,
                              const int* __restrict__ bsum,
                              int2* __restrict__ dso, int* __restrict__ org) {
  const int xcd = blockIdx.x & 7;
  const int e   = (blockIdx.x >> 3) * 256 + threadIdx.x;
  const int d   = ei[NE + e];
  if (d / NPX != xcd) return;
  const int p = atomicAdd(&head[d], 1) + bsum[d >> 9];
  dso[p] = make_int2(d, ei[e]);
  org[p] = e;
}

// gather ea rows (full-line random reads, no RMW) -> fully coalesced eas writes
__global__ void k_ea_gather(const int* __restrict__ org, const float* __restrict__ ea,
                            bf16_t* __restrict__ eas) {
  int p = blockIdx.x * 256 + threadIdx.x;
  if (p >= NE) return;
  const float* pa = ea + (size_t)org[p] * ED;
  bf16_t* pe = eas + (size_t)p * ED;
  #pragma unroll
  for (int q = 0; q < ED; q += 8) {
    float4 x0 = *(const float4*)(pa + q), x1 = *(const float4*)(pa + q + 4);
    union { bf16_t h[8]; uint4 u; } pk;
    pk.h[0] = (bf16_t)x0.x; pk.h[1] = (bf16_t)x0.y; pk.h[2] = (bf16_t)x0.z; pk.h[3] = (bf16_t)x0.w;
    pk.h[4] = (bf16_t)x1.x; pk.h[5] = (bf16_t)x1.y; pk.h[6] = (bf16_t)x1.z; pk.h[7] = (bf16_t)x1.w;
    *(uint4*)(pe + q) = pk.u;
  }
}

// 512 threads, 8 waves, 256 edges/block (32 edge-rows per wave) — frozen structure
// (R10/R13/R16): contiguous-k A-gather (10x dwordx4/lane), pre-fragmented B in LDS,
// one barrier, in-register epilogue + ballot-driven segmented reduction.
// Registers: ~60 arch VGPR + 64 AGPR acc -> 2 blocks/CU is the structural ceiling
// (R4 & R11 both proved forcing 6 waves/EU spills to scratch: WRITE_SIZE 0.5-3.4 GB).
__launch_bounds__(512, 4)
__global__ void k_edges(const int2* __restrict__ dso, const bf16_t* __restrict__ eas,
                        const bf16_t* __restrict__ hb, const bf16_t* __restrict__ Wt,
                        const float* __restrict__ bfv, const float* __restrict__ bsv,
                        float* __restrict__ agg, int layer) {
  extern __shared__ char smem[];
  bf16_t* Bsh = (bf16_t*)smem;                       // [20480] pre-fragmented W

  const int tid = threadIdx.x;

  // bijective XCD-chunked swizzle: consecutive work -> same XCD (sorted-dst L2 locality)
  // NWG = 6250 = 8*781 + 2 -> q=781, r=2
  const int orig = blockIdx.x;
  const int xcd  = orig & 7;
  const int wg   = ((xcd < 2) ? xcd * 782 : 2 * 782 + (xcd - 2) * 781) + (orig >> 3);
  const int e0   = wg * 256;

  const int w  = tid >> 6;
  const int l  = tid & 63;
  const int lr = l & 31;
  const int g  = l >> 5;
  const int e  = w * 32 + lr;

  // long-latency loads first: one 8B load for (dst,src)
  const int2 dsv = dso[e0 + e];
  const int dv = dsv.x;
  const int sv = dsv.y;

  // per-lane bias values (folded into acc init via MFMA C-in)
  const float* bfl = bfv + layer * F;
  const float* bsl = bsv + layer * F;
  const float b0 = bfl[lr], b1 = bfl[lr + 32];
  const float s0b = bsl[lr], s1b = bsl[lr + 32];

  // A-gather, contiguous-k layout: lane's g-half owns k[g*32,(g+1)*32) of each 64-elem row
  // (e: k[g*16,(g+1)*16)) -> 16B-contiguous chunks; fragment ks = frag[ks] directly.
  uint4 frag[10];
  {
    const char* dp = (const char*)(hb + (size_t)dv * F) + g * 64;
    const char* sp = (const char*)(hb + (size_t)sv * F) + g * 64;
    const char* ep = (const char*)(eas + (size_t)(e0 + e) * ED) + g * 32;
    #pragma unroll
    for (int j = 0; j < 4; ++j) frag[j] = *(const uint4*)(dp + j * 16);
    #pragma unroll
    for (int j = 0; j < 4; ++j) frag[4 + j] = *(const uint4*)(sp + j * 16);
    frag[8] = *(const uint4*)(ep);
    frag[9] = *(const uint4*)(ep + 16);
  }

  // stage B: 40960 B = 2560 uint4, 5 per thread
  {
    const uint4* Wg = (const uint4*)(Wt + (size_t)layer * NC * ZIN);
    uint4 breg[5];
    #pragma unroll
    for (int t = 0; t < 5; ++t) breg[t] = Wg[tid + t * 512];
    uint4* Bv = (uint4*)Bsh;
    #pragma unroll
    for (int t = 0; t < 5; ++t) Bv[tid + t * 512] = breg[t];
  }
  __syncthreads();   // the ONLY barrier: Bsh visible to all waves

  f32x16 acc[4];
  #pragma unroll
  for (int q = 0; q < 16; ++q) { acc[0][q] = b0; acc[1][q] = b1; acc[2][q] = s0b; acc[3][q] = s1b; }

  // independent-wave regime post-barrier -> setprio around MFMA cluster
  __builtin_amdgcn_s_setprio(1);
  #pragma unroll
  for (int ks = 0; ks < 10; ++ks) {
    union { uint4 u; bf16x8 v; } a;
    a.u = frag[ks];
    #pragma unroll
    for (int n = 0; n < 4; ++n) {
      bf16x8 b = *(const bf16x8*)(Bsh + ((ks * 4 + n) * 64 + l) * 8);  // ds_read_b128, stride-1
      acc[n] = __builtin_amdgcn_mfma_f32_32x32x16_bf16(a.v, b, acc[n], 0, 0, 0);
    }
  }
  __builtin_amdgcn_s_setprio(0);

  // epilogue in registers: mv0[q] = m[row(q,g)][lr], mv1[q] = m[row(q,g)][32+lr]
  const float L2E = 1.4426950408889634f, LN2 = 0.6931471805599453f;
  float mv0[16], mv1[16];
  #pragma unroll
  for (int q = 0; q < 16; ++q) {
    float f0 = acc[0][q], f1 = acc[1][q];
    float s2a = acc[2][q], s2c = acc[3][q];
    float sg0 = __builtin_amdgcn_rcpf(1.0f + __builtin_amdgcn_exp2f(-f0 * L2E));
    float sg1 = __builtin_amdgcn_rcpf(1.0f + __builtin_amdgcn_exp2f(-f1 * L2E));
    float sp0 = fmaxf(s2a, 0.0f) + __builtin_amdgcn_logf(1.0f + __builtin_amdgcn_exp2f(-fabsf(s2a) * L2E)) * LN2;
    float sp1 = fmaxf(s2c, 0.0f) + __builtin_amdgcn_logf(1.0f + __builtin_amdgcn_exp2f(-fabsf(s2c) * L2E)) * LN2;
    mv0[q] = sg0 * sp0;
    mv1[q] = sg1 * sp1;
  }

  // in-register segmented reduction over sorted-dst runs within this wave's 32-row window
  {
    const int dvp = __shfl(dv, l - 1);   // previous row's dst (lr>0 only)
    uint32_t bmask = ((uint32_t)__ballot(lr > 0 && dv != dvp)) | 1u;
    while (bmask) {
      const int a = __ffs(bmask) - 1;
      bmask &= bmask - 1;
      const int b = bmask ? (__ffs(bmask) - 1) : 32;
      const int dcur = __shfl(dv, a);
      float r0 = 0.0f, r1 = 0.0f;
      #pragma unroll
      for (int q = 0; q < 16; ++q) {
        const int row = (q & 3) + 8 * (q >> 2) + 4 * g;   // verified 32x32 C/D row map
        const bool in = (row >= a) && (row < b);
        r0 += in ? mv0[q] : 0.0f;
        r1 += in ? mv1[q] : 0.0f;
      }
      r0 += __shfl_xor(r0, 32);
      r1 += __shfl_xor(r1, 32);
      if (g == 0) {
        atomicAdd(agg + (size_t)dcur * F + lr,      r0);
        atomicAdd(agg + (size_t)dcur * F + 32 + lr, r1);
      }
    }
  }
}

__global__ void k_update(float4* __restrict__ agg4, const float* __restrict__ gam,
                         const float* __restrict__ bet, const float* __restrict__ mu,
                         const float* __restrict__ var, float4* __restrict__ h4,
                         ushort4* __restrict__ hb4, int layer) {
  int i = blockIdx.x * 256 + threadIdx.x;     // NN*F/4 = 800000
  if (i >= NN * F / 4) return;
  int c4 = (i * 4) & 63;
  float4 G = *(const float4*)(gam + layer * F + c4);
  float4 B = *(const float4*)(bet + layer * F + c4);
  float4 M = *(const float4*)(mu  + layer * F + c4);
  float4 V = *(const float4*)(var + layer * F + c4);
  float4 a = agg4[i];
  float4 h = h4[i];
  float4 o;
  float scx = G.x * rsqrtf(V.x + BN_EPS), scy = G.y * rsqrtf(V.y + BN_EPS);
  float scz = G.z * rsqrtf(V.z + BN_EPS), scw = G.w * rsqrtf(V.w + BN_EPS);
  o.x = fmaxf(a.x * scx + (B.x - M.x * scx) + h.x, 0.0f);
  o.y = fmaxf(a.y * scy + (B.y - M.y * scy) + h.y, 0.0f);
  o.z = fmaxf(a.z * scz + (B.z - M.z * scz) + h.z, 0.0f);
  o.w = fmaxf(a.w * scw + (B.w - M.w * scw) + h.w, 0.0f);
  agg4[i] = make_float4(0.f, 0.f, 0.f, 0.f);   // pre-zero for next layer
  h4[i] = o;
  union { bf16_t h[4]; ushort4 u; } pk;
  pk.h[0] = (bf16_t)o.x; pk.h[1] = (bf16_t)o.y; pk.h[2] = (bf16_t)o.z; pk.h[3] = (bf16_t)o.w;
  hb4[i] = pk.u;
}

__device__ __forceinline__ int lowb(const int* a, int n, int v) {
  int lo = 0, hi = n;
  while (lo < hi) { int mid = (lo + hi) >> 1; if (a[mid] < v) lo = mid + 1; else hi = mid; }
  return lo;
}

// final layer fused: pool = mean over relu(BN(agg) + h32), then 2-layer MLP
__global__ void k_pool_mlp(const float* __restrict__ agg, const float* __restrict__ h32,
                           const float* __restrict__ gam, const float* __restrict__ bet,
                           const float* __restrict__ mu, const float* __restrict__ var,
                           const int* __restrict__ batch,
                           const float* __restrict__ W1, const float* __restrict__ b1,
                           const float* __restrict__ W2, const float* __restrict__ b2,
                           float* __restrict__ out) {
  __shared__ float pooled[F];
  __shared__ float ps[HF];
  __shared__ float red[HF];
  const int gph = blockIdx.x;
  const int t = threadIdx.x;   // 128 threads
  const int c = t & 63;
  const int lo = lowb(batch, NN, gph);
  const int hi = lowb(batch, NN, gph + 1);

  const int L = NCONV - 1;
  const float sc = gam[L * F + c] * rsqrtf(var[L * F + c] + BN_EPS);
  const float sh = bet[L * F + c] - mu[L * F + c] * sc;

  float s = 0.f;
  for (int i = lo + (t >> 6); i < hi; i += 2) {
    float v = agg[(size_t)i * F + c] * sc + sh + h32[(size_t)i * F + c];
    s += fmaxf(v, 0.0f);
  }
  ps[t] = s;
  __syncthreads();
  if (t < F) {
    float tot = ps[t] + ps[t + F];
    pooled[t] = tot / fmaxf((float)(hi - lo), 1.0f);
  }
  __syncthreads();

  float a = b1[t];
  for (int cc = 0; cc < F; ++cc) a += pooled[cc] * W1[cc * HF + t];
  a = fmaxf(a, 0.f);
  red[t] = a * W2[t];
  __syncthreads();
  for (int sdv = 64; sdv > 0; sdv >>= 1) {
    if (t < sdv) red[t] += red[t + sdv];
    __syncthreads();
  }
  if (t == 0) out[gph] = red[0] + b2[0];
}

extern "C" void kernel_launch(void* const* d_in, const int* in_sizes, int n_in,
                              void* d_out, int out_size, void* d_ws, size_t ws_size,
                              hipStream_t stream) {
  const int*   x    = (const int*)d_in[0];
  const int*   ei   = (const int*)d_in[1];
  const float* ea   = (const float*)d_in[2];
  const int*   batch= (const int*)d_in[3];
  const float* emb  = (const float*)d_in[4];
  const float* Wf   = (const float*)d_in[5];
  const float* bfb  = (const float*)d_in[6];
  const float* Ws   = (const float*)d_in[7];
  const float* bsb  = (const float*)d_in[8];
  const float* gam  = (const float*)d_in[9];
  const float* bet  = (const float*)d_in[10];
  const float* mu   = (const float*)d_in[11];
  const float* var  = (const float*)d_in[12];
  const float* W1   = (const float*)d_in[13];
  const float* b1   = (const float*)d_in[14];
  const float* W2   = (const float*)d_in[15];
  const float* b2   = (const float*)d_in[16];
  float* out = (float*)d_out;

  char* p = (char*)d_ws;
  auto take = [&](size_t bytes) { char* q = p; p += (bytes + 255) & ~(size_t)255; return q; };
  float*  h32  = (float*)take((size_t)NN * F * 4);
  bf16_t* hb   = (bf16_t*)take((size_t)NN * F * 2);
  float*  agg  = (float*)take((size_t)NN * F * 4);
  bf16_t* Wt   = (bf16_t*)take((size_t)NCONV * NC * ZIN * 2);
  int*    cnt  = (int*)take((size_t)NN * 4);
  int*    head = (int*)take((size_t)NN * 4);
  int*    bsum = (int*)take((size_t)128 * 4);
  int2*   dso  = (int2*)take((size_t)NE * 8);
  int*    org  = (int*)take((size_t)NE * 4);
  bf16_t* eas  = (bf16_t*)take((size_t)NE * ED * 2);

  hipMemsetAsync(cnt, 0, (size_t)NN * 4, stream);
  k_embed_hist<<<(NN * F / 4 + 255) / 256, 256, 0, stream>>>(x, emb, (float4*)h32,
                                                             (ushort4*)hb, ei, cnt, (float4*)agg);
  k_wprep<<<(NCONV * ZIN * NC + 255) / 256, 256, 0, stream>>>(Wf, Ws, Wt);

  k_scanA<<<SCB, 512, 0, stream>>>(cnt, head, bsum);
  k_scanB<<<1, 128, 0, stream>>>(bsum);
  k_scatter_idx<<<NWG * 8, 256, 0, stream>>>(ei, head, bsum, dso, org);
  k_ea_gather<<<(NE + 255) / 256, 256, 0, stream>>>(org, ea, eas);

  const size_t smem = 40960;  // Bsh only
  hipFuncSetAttribute((const void*)k_edges, hipFuncAttributeMaxDynamicSharedMemorySize, (int)smem);

  for (int layer = 0; layer < NCONV; ++layer) {
    k_edges<<<NWG, 512, smem, stream>>>(dso, eas, hb, Wt, bfb, bsb, agg, layer);
    if (layer < NCONV - 1)
      k_update<<<(NN * F / 4 + 255) / 256, 256, 0, stream>>>((float4*)agg, gam, bet, mu, var,
                                                             (float4*)h32, (ushort4*)hb, layer);
  }

  k_pool_mlp<<<NG, HF, 0, stream>>>(agg, h32, gam, bet, mu, var, batch, W1, b1, W2, b2, out);
}